// Round 1
// baseline (826.262 us; speedup 1.0000x reference)
//
#include <hip/hip_runtime.h>
#include <hip/hip_bf16.h>

#define N_NODES_C 50000
#define N_EDGES_C 800000
#define IN_DIM_C 64
#define HID_C 256
#define EDGE_DIM_C 6
#define NEG_SLOPE_C 0.2f
#define MAXDEG 1024

// ---------------- v = We @ att_e (6 scalars per layer) ----------------
__global__ void k_v12(const float* __restrict__ We1, const float* __restrict__ atte1,
                      const float* __restrict__ We2, const float* __restrict__ atte2,
                      float* __restrict__ v) {
    __shared__ float red[256];
    int tid = threadIdx.x;
    for (int layer = 0; layer < 2; ++layer) {
        const float* We  = layer ? We2  : We1;
        const float* ae  = layer ? atte2 : atte1;
        for (int k = 0; k < EDGE_DIM_C; ++k) {
            red[tid] = We[k * HID_C + tid] * ae[tid];
            __syncthreads();
            for (int s = 128; s > 0; s >>= 1) {
                if (tid < s) red[tid] += red[tid + s];
                __syncthreads();
            }
            if (tid == 0) v[layer * 8 + k] = red[0];
            __syncthreads();
        }
    }
}

// ---------------- degree histogram over dst ----------------
__global__ void k_hist(const int* __restrict__ dst, int* __restrict__ deg) {
    int i = blockIdx.x * blockDim.x + threadIdx.x;
    int stride = gridDim.x * blockDim.x;
    for (int e = i; e < N_EDGES_C; e += stride) atomicAdd(&deg[dst[e]], 1);
}

// ---------------- single-block exclusive scan (1024 threads) ----------------
__global__ void k_scan(const int* __restrict__ deg, int* __restrict__ offs) {
    __shared__ int tmp[1024];
    __shared__ int carry_s;
    int tid = threadIdx.x;
    if (tid == 0) carry_s = 0;
    __syncthreads();
    for (int base = 0; base < N_NODES_C; base += 1024) {
        int i = base + tid;
        int val = (i < N_NODES_C) ? deg[i] : 0;
        tmp[tid] = val;
        __syncthreads();
        for (int d = 1; d < 1024; d <<= 1) {
            int t = (tid >= d) ? tmp[tid - d] : 0;
            __syncthreads();
            tmp[tid] += t;
            __syncthreads();
        }
        if (i < N_NODES_C) offs[i] = carry_s + tmp[tid] - val;  // exclusive
        __syncthreads();
        if (tid == 0) carry_s += tmp[1023];
        __syncthreads();
    }
    if (tid == 0) offs[N_NODES_C] = carry_s;
}

// ---------------- scatter edges into CSR order + per-edge a_edge ----------------
__global__ void k_scatter(const int* __restrict__ src, const int* __restrict__ dst,
                          const float* __restrict__ eattr, const int* __restrict__ offs,
                          int* __restrict__ cur, const float* __restrict__ v,
                          int* __restrict__ ssrc, float* __restrict__ sae1,
                          float* __restrict__ sae2) {
    int i = blockIdx.x * blockDim.x + threadIdx.x;
    int stride = gridDim.x * blockDim.x;
    for (int e = i; e < N_EDGES_C; e += stride) {
        int d = dst[e];
        int pos = offs[d] + atomicAdd(&cur[d], 1);
        ssrc[pos] = src[e];
        float a1 = 0.f, a2 = 0.f;
#pragma unroll
        for (int k = 0; k < EDGE_DIM_C; ++k) {
            float ea = eattr[e * EDGE_DIM_C + k];
            a1 += ea * v[k];
            a2 += ea * v[8 + k];
        }
        sae1[pos] = a1;
        sae2[pos] = a2;
    }
}

// ---------------- tiled f32 GEMM: H[n,256] = X[n,K] @ W[K,256] ----------------
template <int K>
__global__ __launch_bounds__(256) void k_gemm(const float* __restrict__ X,
                                              const float* __restrict__ W,
                                              float* __restrict__ H) {
    __shared__ float xs[16 * K];
    int tid = threadIdx.x;
    int base = blockIdx.x * 16;
    for (int idx = tid; idx < 16 * K; idx += 256) {
        int r = idx / K, k = idx % K;
        int node = base + r;
        xs[idx] = (node < N_NODES_C) ? X[(long)node * K + k] : 0.f;
    }
    __syncthreads();
    float acc[16];
#pragma unroll
    for (int r = 0; r < 16; ++r) acc[r] = 0.f;
    for (int k = 0; k < K; ++k) {
        float w = W[k * HID_C + tid];
#pragma unroll
        for (int r = 0; r < 16; ++r) acc[r] += xs[r * K + k] * w;
    }
#pragma unroll
    for (int r = 0; r < 16; ++r) {
        int node = base + r;
        if (node < N_NODES_C) H[(long)node * HID_C + tid] = acc[r];
    }
}

// ---------------- per-node dots: a_src[i]=h_i.att_s, a_dst[i]=h_i.att_d ----------------
__global__ void k_dots(const float* __restrict__ H, const float* __restrict__ att_s,
                       const float* __restrict__ att_d, float* __restrict__ asrc,
                       float* __restrict__ adst) {
    int wave = threadIdx.x >> 6;
    int lane = threadIdx.x & 63;
    int node = blockIdx.x * 4 + wave;
    if (node >= N_NODES_C) return;
    float s = 0.f, d = 0.f;
#pragma unroll
    for (int j = 0; j < 4; ++j) {
        int c = lane + j * 64;
        float h = H[(long)node * HID_C + c];
        s += h * att_s[c];
        d += h * att_d[c];
    }
    for (int off = 32; off > 0; off >>= 1) {
        s += __shfl_down(s, off);
        d += __shfl_down(d, off);
    }
    if (lane == 0) {
        asrc[node] = s;
        adst[node] = d;
    }
}

// ---------------- per-dst-node softmax + weighted aggregation ----------------
__global__ __launch_bounds__(256) void k_aggr(const int* __restrict__ offs,
                                              const int* __restrict__ ssrc,
                                              const float* __restrict__ sae,
                                              const float* __restrict__ asrc,
                                              const float* __restrict__ adst,
                                              const float* __restrict__ H,
                                              const float* __restrict__ bias,
                                              float* __restrict__ out, int do_relu) {
    __shared__ float red[256];
    __shared__ float wts[MAXDEG];
    int i = blockIdx.x;
    int tid = threadIdx.x;
    int off0 = offs[i], off1 = offs[i + 1];
    float adi = adst[i];

    // phase A: leaky-relu'd logits + block max
    float lmax = -3.4e38f;
    for (int e = off0 + tid; e < off1; e += 256) {
        float a = asrc[ssrc[e]] + adi + sae[e];
        a = (a > 0.f) ? a : NEG_SLOPE_C * a;
        int j = e - off0;
        if (j < MAXDEG) wts[j] = a;
        lmax = fmaxf(lmax, a);
    }
    red[tid] = lmax;
    __syncthreads();
    for (int s = 128; s > 0; s >>= 1) {
        if (tid < s) red[tid] = fmaxf(red[tid], red[tid + s]);
        __syncthreads();
    }
    float m = red[0];
    __syncthreads();

    // phase B: exp + block sum
    float lsum = 0.f;
    for (int e = off0 + tid; e < off1; e += 256) {
        int j = e - off0;
        float a;
        if (j < MAXDEG) a = wts[j];
        else {
            a = asrc[ssrc[e]] + adi + sae[e];
            a = (a > 0.f) ? a : NEG_SLOPE_C * a;
        }
        float ex = __expf(a - m);
        if (j < MAXDEG) wts[j] = ex;
        lsum += ex;
    }
    red[tid] = lsum;
    __syncthreads();
    for (int s = 128; s > 0; s >>= 1) {
        if (tid < s) red[tid] += red[tid + s];
        __syncthreads();
    }
    float inv = 1.0f / (red[0] + 1e-16f);
    __syncthreads();

    // phase C: acc_c = sum_e w_e * H[src_e][c]
    float acc = 0.f;
    for (int e = off0; e < off1; ++e) {
        int j = e - off0;
        float w;
        if (j < MAXDEG) w = wts[j];
        else {
            float a = asrc[ssrc[e]] + adi + sae[e];
            a = (a > 0.f) ? a : NEG_SLOPE_C * a;
            w = __expf(a - m);
        }
        acc += w * H[(long)ssrc[e] * HID_C + tid];
    }
    acc = acc * inv + bias[tid];
    if (do_relu) acc = fmaxf(acc, 0.f);
    out[(long)i * HID_C + tid] = acc;
}

extern "C" void kernel_launch(void* const* d_in, const int* in_sizes, int n_in,
                              void* d_out, int out_size, void* d_ws, size_t ws_size,
                              hipStream_t stream) {
    const float* x     = (const float*)d_in[0];
    const int*   ei    = (const int*)d_in[1];     // [2, E]: row0=src, row1=dst
    const float* eattr = (const float*)d_in[2];
    const float* W1    = (const float*)d_in[3];
    const float* atts1 = (const float*)d_in[4];
    const float* attd1 = (const float*)d_in[5];
    const float* We1   = (const float*)d_in[6];
    const float* atte1 = (const float*)d_in[7];
    const float* b1    = (const float*)d_in[8];
    const float* W2    = (const float*)d_in[9];
    const float* atts2 = (const float*)d_in[10];
    const float* attd2 = (const float*)d_in[11];
    const float* We2   = (const float*)d_in[12];
    const float* atte2 = (const float*)d_in[13];
    const float* b2    = (const float*)d_in[14];
    float* out = (float*)d_out;

    char* ws = (char*)d_ws;
    size_t off = 0;
    auto alloc = [&](size_t bytes) -> void* {
        void* p = ws + off;
        off = (off + bytes + 255) & ~(size_t)255;
        return p;
    };
    int*   deg  = (int*)alloc((size_t)N_NODES_C * 4);
    int*   offs = (int*)alloc(((size_t)N_NODES_C + 1) * 4);
    int*   cur  = (int*)alloc((size_t)N_NODES_C * 4);
    int*   ssrc = (int*)alloc((size_t)N_EDGES_C * 4);
    float* sae1 = (float*)alloc((size_t)N_EDGES_C * 4);
    float* sae2 = (float*)alloc((size_t)N_EDGES_C * 4);
    float* asrc = (float*)alloc((size_t)N_NODES_C * 4);
    float* adst = (float*)alloc((size_t)N_NODES_C * 4);
    float* v    = (float*)alloc(64);
    float* hbuf = (float*)alloc((size_t)N_NODES_C * HID_C * 4);

    const int* src = ei;
    const int* dst = ei + N_EDGES_C;

    hipMemsetAsync(deg, 0, (size_t)N_NODES_C * 4, stream);
    hipMemsetAsync(cur, 0, (size_t)N_NODES_C * 4, stream);

    k_v12<<<1, 256, 0, stream>>>(We1, atte1, We2, atte2, v);
    k_hist<<<1024, 256, 0, stream>>>(dst, deg);
    k_scan<<<1, 1024, 0, stream>>>(deg, offs);
    k_scatter<<<1024, 256, 0, stream>>>(src, dst, eattr, offs, cur, v, ssrc, sae1, sae2);

    // layer 1
    k_gemm<IN_DIM_C><<<(N_NODES_C + 15) / 16, 256, 0, stream>>>(x, W1, hbuf);
    k_dots<<<(N_NODES_C + 3) / 4, 256, 0, stream>>>(hbuf, atts1, attd1, asrc, adst);
    k_aggr<<<N_NODES_C, 256, 0, stream>>>(offs, ssrc, sae1, asrc, adst, hbuf, b1, out, 1);

    // layer 2 (reads layer-1 activations from d_out, overwrites hbuf, then d_out)
    k_gemm<HID_C><<<(N_NODES_C + 15) / 16, 256, 0, stream>>>(out, W2, hbuf);
    k_dots<<<(N_NODES_C + 3) / 4, 256, 0, stream>>>(hbuf, atts2, attd2, asrc, adst);
    k_aggr<<<N_NODES_C, 256, 0, stream>>>(offs, ssrc, sae2, asrc, adst, hbuf, b2, out, 0);
}

// Round 2
// 703.701 us; speedup vs baseline: 1.1742x; 1.1742x over previous
//
#include <hip/hip_runtime.h>
#include <hip/hip_bf16.h>

#define N_NODES_C 50000
#define N_EDGES_C 800000
#define IN_DIM_C 64
#define HID_C 256
#define EDGE_DIM_C 6
#define NEG_SLOPE_C 0.2f
#define MAXDEG 512

// ---------------- v = We @ att_e (6 scalars per layer) ----------------
__global__ void k_v12(const float* __restrict__ We1, const float* __restrict__ atte1,
                      const float* __restrict__ We2, const float* __restrict__ atte2,
                      float* __restrict__ v) {
    __shared__ float red[256];
    int tid = threadIdx.x;
    for (int layer = 0; layer < 2; ++layer) {
        const float* We  = layer ? We2  : We1;
        const float* ae  = layer ? atte2 : atte1;
        for (int k = 0; k < EDGE_DIM_C; ++k) {
            red[tid] = We[k * HID_C + tid] * ae[tid];
            __syncthreads();
            for (int s = 128; s > 0; s >>= 1) {
                if (tid < s) red[tid] += red[tid + s];
                __syncthreads();
            }
            if (tid == 0) v[layer * 8 + k] = red[0];
            __syncthreads();
        }
    }
}

// ---------------- degree histogram over dst ----------------
__global__ void k_hist(const int* __restrict__ dst, int* __restrict__ deg) {
    int i = blockIdx.x * blockDim.x + threadIdx.x;
    int stride = gridDim.x * blockDim.x;
    for (int e = i; e < N_EDGES_C; e += stride) atomicAdd(&deg[dst[e]], 1);
}

// ---------------- single-block exclusive scan (1024 threads) ----------------
__global__ void k_scan(const int* __restrict__ deg, int* __restrict__ offs) {
    __shared__ int tmp[1024];
    __shared__ int carry_s;
    int tid = threadIdx.x;
    if (tid == 0) carry_s = 0;
    __syncthreads();
    for (int base = 0; base < N_NODES_C; base += 1024) {
        int i = base + tid;
        int val = (i < N_NODES_C) ? deg[i] : 0;
        tmp[tid] = val;
        __syncthreads();
        for (int d = 1; d < 1024; d <<= 1) {
            int t = (tid >= d) ? tmp[tid - d] : 0;
            __syncthreads();
            tmp[tid] += t;
            __syncthreads();
        }
        if (i < N_NODES_C) offs[i] = carry_s + tmp[tid] - val;  // exclusive
        __syncthreads();
        if (tid == 0) carry_s += tmp[1023];
        __syncthreads();
    }
    if (tid == 0) offs[N_NODES_C] = carry_s;
}

// ---------------- scatter edges into CSR order + per-edge a_edge ----------------
__global__ void k_scatter(const int* __restrict__ src, const int* __restrict__ dst,
                          const float* __restrict__ eattr, const int* __restrict__ offs,
                          int* __restrict__ cur, const float* __restrict__ v,
                          int* __restrict__ ssrc, float* __restrict__ sae1,
                          float* __restrict__ sae2) {
    int i = blockIdx.x * blockDim.x + threadIdx.x;
    int stride = gridDim.x * blockDim.x;
    for (int e = i; e < N_EDGES_C; e += stride) {
        int d = dst[e];
        int pos = offs[d] + atomicAdd(&cur[d], 1);
        ssrc[pos] = src[e];
        float a1 = 0.f, a2 = 0.f;
#pragma unroll
        for (int k = 0; k < EDGE_DIM_C; ++k) {
            float ea = eattr[e * EDGE_DIM_C + k];
            a1 += ea * v[k];
            a2 += ea * v[8 + k];
        }
        sae1[pos] = a1;
        sae2[pos] = a2;
    }
}

// ---------------- GEMM: H[n,256] = X[n,K] @ W[K,256], X read via SGPR ----------------
// 50000 % 16 == 0, so no tail guards.
template <int K>
__global__ __launch_bounds__(256) void k_gemm(const float* __restrict__ X,
                                              const float* __restrict__ W,
                                              float* __restrict__ H) {
    int tid = threadIdx.x;
    long base = (long)blockIdx.x * 16;
    const float* Xb = X + base * K;   // block-uniform base -> scalar loads
    float acc[16];
#pragma unroll
    for (int r = 0; r < 16; ++r) acc[r] = 0.f;
    for (int k = 0; k < K; k += 4) {
        float w0 = W[(k + 0) * HID_C + tid];
        float w1 = W[(k + 1) * HID_C + tid];
        float w2 = W[(k + 2) * HID_C + tid];
        float w3 = W[(k + 3) * HID_C + tid];
#pragma unroll
        for (int r = 0; r < 16; ++r) {
            float4 xv = *reinterpret_cast<const float4*>(&Xb[r * K + k]);
            acc[r] = fmaf(xv.x, w0, fmaf(xv.y, w1, fmaf(xv.z, w2, fmaf(xv.w, w3, acc[r]))));
        }
    }
#pragma unroll
    for (int r = 0; r < 16; ++r) H[(base + r) * HID_C + tid] = acc[r];
}

// ---------------- per-node dots: a_src[i]=h_i.att_s, a_dst[i]=h_i.att_d ----------------
__global__ void k_dots(const float* __restrict__ H, const float* __restrict__ att_s,
                       const float* __restrict__ att_d, float* __restrict__ asrc,
                       float* __restrict__ adst) {
    int wave = threadIdx.x >> 6;
    int lane = threadIdx.x & 63;
    int node = blockIdx.x * 4 + wave;
    if (node >= N_NODES_C) return;
    float s = 0.f, d = 0.f;
#pragma unroll
    for (int j = 0; j < 4; ++j) {
        int c = lane + j * 64;
        float h = H[(long)node * HID_C + c];
        s += h * att_s[c];
        d += h * att_d[c];
    }
    for (int off = 32; off > 0; off >>= 1) {
        s += __shfl_down(s, off);
        d += __shfl_down(d, off);
    }
    if (lane == 0) {
        asrc[node] = s;
        adst[node] = d;
    }
}

// ---------------- per-dst-node softmax + weighted aggregation ----------------
// Phase C: 4 waves x every-4th-edge, float4 per lane, 2-deep unroll -> 8 rows
// in flight per block; cross-wave LDS reduction at the end.
__global__ __launch_bounds__(256) void k_aggr(const int* __restrict__ offs,
                                              const int* __restrict__ ssrc,
                                              const float* __restrict__ sae,
                                              const float* __restrict__ asrc,
                                              const float* __restrict__ adst,
                                              const float* __restrict__ H,
                                              const float* __restrict__ bias,
                                              float* __restrict__ out, int do_relu) {
    __shared__ float red[256];
    __shared__ float wts[MAXDEG];
    __shared__ float pacc[4][HID_C];
    int i = blockIdx.x;
    int tid = threadIdx.x;
    int off0 = offs[i], off1 = offs[i + 1];
    int deg = off1 - off0;
    float adi = adst[i];

    // phase A: leaky-relu'd logits + block max
    float lmax = -3.4e38f;
    for (int j = tid; j < deg; j += 256) {
        float a = asrc[ssrc[off0 + j]] + adi + sae[off0 + j];
        a = (a > 0.f) ? a : NEG_SLOPE_C * a;
        if (j < MAXDEG) wts[j] = a;
        lmax = fmaxf(lmax, a);
    }
    red[tid] = lmax;
    __syncthreads();
    for (int s = 128; s > 0; s >>= 1) {
        if (tid < s) red[tid] = fmaxf(red[tid], red[tid + s]);
        __syncthreads();
    }
    float m = red[0];
    __syncthreads();

    // phase B: exp + block sum
    float lsum = 0.f;
    for (int j = tid; j < deg; j += 256) {
        float a;
        if (j < MAXDEG) a = wts[j];
        else {
            a = asrc[ssrc[off0 + j]] + adi + sae[off0 + j];
            a = (a > 0.f) ? a : NEG_SLOPE_C * a;
        }
        float ex = __expf(a - m);
        if (j < MAXDEG) wts[j] = ex;
        lsum += ex;
    }
    red[tid] = lsum;
    __syncthreads();
    for (int s = 128; s > 0; s >>= 1) {
        if (tid < s) red[tid] += red[tid + s];
        __syncthreads();
    }
    float inv = 1.0f / (red[0] + 1e-16f);
    __syncthreads();

    // phase C: wave w handles edges j = w, w+4, w+8, ... ; float4 per lane
    int w = tid >> 6, lane = tid & 63;
    float ax = 0.f, ay = 0.f, az = 0.f, aw = 0.f;
    int col4 = lane * 4;
    int j = w;
    for (; j + 4 < deg; j += 8) {
        int s0 = ssrc[off0 + j];
        int s1 = ssrc[off0 + j + 4];
        float w0, w1;
        if (j < MAXDEG) w0 = wts[j];
        else {
            float a = asrc[s0] + adi + sae[off0 + j];
            a = (a > 0.f) ? a : NEG_SLOPE_C * a;
            w0 = __expf(a - m);
        }
        if (j + 4 < MAXDEG) w1 = wts[j + 4];
        else {
            float a = asrc[s1] + adi + sae[off0 + j + 4];
            a = (a > 0.f) ? a : NEG_SLOPE_C * a;
            w1 = __expf(a - m);
        }
        float4 h0 = *reinterpret_cast<const float4*>(&H[(long)s0 * HID_C + col4]);
        float4 h1 = *reinterpret_cast<const float4*>(&H[(long)s1 * HID_C + col4]);
        ax += w0 * h0.x + w1 * h1.x;
        ay += w0 * h0.y + w1 * h1.y;
        az += w0 * h0.z + w1 * h1.z;
        aw += w0 * h0.w + w1 * h1.w;
    }
    if (j < deg) {
        int s0 = ssrc[off0 + j];
        float w0;
        if (j < MAXDEG) w0 = wts[j];
        else {
            float a = asrc[s0] + adi + sae[off0 + j];
            a = (a > 0.f) ? a : NEG_SLOPE_C * a;
            w0 = __expf(a - m);
        }
        float4 h0 = *reinterpret_cast<const float4*>(&H[(long)s0 * HID_C + col4]);
        ax += w0 * h0.x;
        ay += w0 * h0.y;
        az += w0 * h0.z;
        aw += w0 * h0.w;
    }
    pacc[w][col4 + 0] = ax;
    pacc[w][col4 + 1] = ay;
    pacc[w][col4 + 2] = az;
    pacc[w][col4 + 3] = aw;
    __syncthreads();

    float acc = pacc[0][tid] + pacc[1][tid] + pacc[2][tid] + pacc[3][tid];
    acc = acc * inv + bias[tid];
    if (do_relu) acc = fmaxf(acc, 0.f);
    out[(long)i * HID_C + tid] = acc;
}

extern "C" void kernel_launch(void* const* d_in, const int* in_sizes, int n_in,
                              void* d_out, int out_size, void* d_ws, size_t ws_size,
                              hipStream_t stream) {
    const float* x     = (const float*)d_in[0];
    const int*   ei    = (const int*)d_in[1];     // [2, E]: row0=src, row1=dst
    const float* eattr = (const float*)d_in[2];
    const float* W1    = (const float*)d_in[3];
    const float* atts1 = (const float*)d_in[4];
    const float* attd1 = (const float*)d_in[5];
    const float* We1   = (const float*)d_in[6];
    const float* atte1 = (const float*)d_in[7];
    const float* b1    = (const float*)d_in[8];
    const float* W2    = (const float*)d_in[9];
    const float* atts2 = (const float*)d_in[10];
    const float* attd2 = (const float*)d_in[11];
    const float* We2   = (const float*)d_in[12];
    const float* atte2 = (const float*)d_in[13];
    const float* b2    = (const float*)d_in[14];
    float* out = (float*)d_out;

    char* ws = (char*)d_ws;
    size_t off = 0;
    auto alloc = [&](size_t bytes) -> void* {
        void* p = ws + off;
        off = (off + bytes + 255) & ~(size_t)255;
        return p;
    };
    int*   deg  = (int*)alloc((size_t)N_NODES_C * 4);
    int*   offs = (int*)alloc(((size_t)N_NODES_C + 1) * 4);
    int*   cur  = (int*)alloc((size_t)N_NODES_C * 4);
    int*   ssrc = (int*)alloc((size_t)N_EDGES_C * 4);
    float* sae1 = (float*)alloc((size_t)N_EDGES_C * 4);
    float* sae2 = (float*)alloc((size_t)N_EDGES_C * 4);
    float* asrc = (float*)alloc((size_t)N_NODES_C * 4);
    float* adst = (float*)alloc((size_t)N_NODES_C * 4);
    float* v    = (float*)alloc(64);
    float* hbuf = (float*)alloc((size_t)N_NODES_C * HID_C * 4);

    const int* src = ei;
    const int* dst = ei + N_EDGES_C;

    hipMemsetAsync(deg, 0, (size_t)N_NODES_C * 4, stream);
    hipMemsetAsync(cur, 0, (size_t)N_NODES_C * 4, stream);

    k_v12<<<1, 256, 0, stream>>>(We1, atte1, We2, atte2, v);
    k_hist<<<1024, 256, 0, stream>>>(dst, deg);
    k_scan<<<1, 1024, 0, stream>>>(deg, offs);
    k_scatter<<<1024, 256, 0, stream>>>(src, dst, eattr, offs, cur, v, ssrc, sae1, sae2);

    // layer 1
    k_gemm<IN_DIM_C><<<N_NODES_C / 16, 256, 0, stream>>>(x, W1, hbuf);
    k_dots<<<(N_NODES_C + 3) / 4, 256, 0, stream>>>(hbuf, atts1, attd1, asrc, adst);
    k_aggr<<<N_NODES_C, 256, 0, stream>>>(offs, ssrc, sae1, asrc, adst, hbuf, b1, out, 1);

    // layer 2 (reads layer-1 activations from d_out, overwrites hbuf, then d_out)
    k_gemm<HID_C><<<N_NODES_C / 16, 256, 0, stream>>>(out, W2, hbuf);
    k_dots<<<(N_NODES_C + 3) / 4, 256, 0, stream>>>(hbuf, atts2, attd2, asrc, adst);
    k_aggr<<<N_NODES_C, 256, 0, stream>>>(offs, ssrc, sae2, asrc, adst, hbuf, b2, out, 0);
}

// Round 3
// 378.122 us; speedup vs baseline: 2.1852x; 1.8610x over previous
//
#include <hip/hip_runtime.h>
#include <hip/hip_bf16.h>

#define N_NODES_C 50000
#define N_EDGES_C 800000
#define IN_DIM_C 64
#define HID_C 256
#define EDGE_DIM_C 6
#define NEG_SLOPE_C 0.2f
#define MAXDEG 128

typedef short short8 __attribute__((ext_vector_type(8)));
typedef float f32x4 __attribute__((ext_vector_type(4)));

static __device__ __forceinline__ float b2f(unsigned short u) {
    union { unsigned int i; float f; } x;
    x.i = ((unsigned int)u) << 16;
    return x.f;
}
static __device__ __forceinline__ unsigned short f2b(float f) {
    union { __hip_bfloat16 h; unsigned short u; } x;
    x.h = __float2bfloat16(f);
    return x.u;
}

// ---------------- prep: W1 [64,256] -> W1t bf16 [256][64]; W2 [256,256] -> W2t bf16 [256][256]
__global__ void k_prep(const float* __restrict__ W1, const float* __restrict__ W2,
                       unsigned short* __restrict__ W1t, unsigned short* __restrict__ W2t) {
    int i = blockIdx.x * blockDim.x + threadIdx.x;
    if (i < IN_DIM_C * HID_C) {
        int k = i >> 8, n = i & 255;
        W1t[n * IN_DIM_C + k] = f2b(W1[i]);
    }
    if (i < HID_C * HID_C) {
        int k = i >> 8, n = i & 255;
        W2t[n * HID_C + k] = f2b(W2[i]);
    }
}

// ---------------- v = We @ att_e (6 scalars per layer) ----------------
__global__ void k_v12(const float* __restrict__ We1, const float* __restrict__ atte1,
                      const float* __restrict__ We2, const float* __restrict__ atte2,
                      float* __restrict__ v) {
    __shared__ float red[256];
    int tid = threadIdx.x;
    for (int layer = 0; layer < 2; ++layer) {
        const float* We = layer ? We2 : We1;
        const float* ae = layer ? atte2 : atte1;
        for (int k = 0; k < EDGE_DIM_C; ++k) {
            red[tid] = We[k * HID_C + tid] * ae[tid];
            __syncthreads();
            for (int s = 128; s > 0; s >>= 1) {
                if (tid < s) red[tid] += red[tid + s];
                __syncthreads();
            }
            if (tid == 0) v[layer * 8 + k] = red[0];
            __syncthreads();
        }
    }
}

// ---------------- degree histogram over dst ----------------
__global__ void k_hist(const int* __restrict__ dst, int* __restrict__ deg) {
    int i = blockIdx.x * blockDim.x + threadIdx.x;
    int stride = gridDim.x * blockDim.x;
    for (int e = i; e < N_EDGES_C; e += stride) atomicAdd(&deg[dst[e]], 1);
}

// ---------------- single-block exclusive scan, 4 elems/thread ----------------
__global__ void k_scan(const int* __restrict__ deg, int* __restrict__ offs) {
    __shared__ int tmp[1024];
    __shared__ int carry_s;
    int tid = threadIdx.x;
    if (tid == 0) carry_s = 0;
    __syncthreads();
    for (int base = 0; base < N_NODES_C; base += 4096) {
        int i0 = base + tid * 4;
        int v0 = (i0 + 0 < N_NODES_C) ? deg[i0 + 0] : 0;
        int v1 = (i0 + 1 < N_NODES_C) ? deg[i0 + 1] : 0;
        int v2 = (i0 + 2 < N_NODES_C) ? deg[i0 + 2] : 0;
        int v3 = (i0 + 3 < N_NODES_C) ? deg[i0 + 3] : 0;
        int s4 = v0 + v1 + v2 + v3;
        tmp[tid] = s4;
        __syncthreads();
        for (int d = 1; d < 1024; d <<= 1) {
            int t = (tid >= d) ? tmp[tid - d] : 0;
            __syncthreads();
            tmp[tid] += t;
            __syncthreads();
        }
        int excl = carry_s + tmp[tid] - s4;
        if (i0 + 0 < N_NODES_C) offs[i0 + 0] = excl;
        if (i0 + 1 < N_NODES_C) offs[i0 + 1] = excl + v0;
        if (i0 + 2 < N_NODES_C) offs[i0 + 2] = excl + v0 + v1;
        if (i0 + 3 < N_NODES_C) offs[i0 + 3] = excl + v0 + v1 + v2;
        __syncthreads();
        if (tid == 0) carry_s += tmp[1023];
        __syncthreads();
    }
    if (tid == 0) offs[N_NODES_C] = carry_s;
}

// ---------------- scatter edges into CSR order + per-edge a_edge ----------------
__global__ void k_scatter(const int* __restrict__ src, const int* __restrict__ dst,
                          const float* __restrict__ eattr, const int* __restrict__ offs,
                          int* __restrict__ cur, const float* __restrict__ v,
                          int* __restrict__ ssrc, float* __restrict__ sae1,
                          float* __restrict__ sae2) {
    int i = blockIdx.x * blockDim.x + threadIdx.x;
    int stride = gridDim.x * blockDim.x;
    for (int e = i; e < N_EDGES_C; e += stride) {
        int d = dst[e];
        int pos = offs[d] + atomicAdd(&cur[d], 1);
        ssrc[pos] = src[e];
        float a1 = 0.f, a2 = 0.f;
#pragma unroll
        for (int k = 0; k < EDGE_DIM_C; ++k) {
            float ea = eattr[e * EDGE_DIM_C + k];
            a1 += ea * v[k];
            a2 += ea * v[8 + k];
        }
        sae1[pos] = a1;
        sae2[pos] = a2;
    }
}

// ---------------- MFMA GEMM: H[M,256] = X[M,KT] @ Wt^T  (Wt is [256 n][KT k] bf16)
// Block: 64 rows x 256 cols, 4 waves (one 64x64 chunk each), 16x16x32 bf16 MFMA.
// LDS XOR-swizzle ((row&7)<<3 in elements) on both write and read sides.
template <int KT, bool SRCF32>
__global__ __launch_bounds__(256) void k_gemm_mfma(const void* __restrict__ Xv,
                                                   const unsigned short* __restrict__ Wt,
                                                   unsigned short* __restrict__ H) {
    __shared__ unsigned short As[64 * 64];   // 8 KB
    __shared__ unsigned short Bs[256 * 64];  // 32 KB
    int tid = threadIdx.x;
    int w = tid >> 6, l = tid & 63;
    int lr = l & 15, lg = l >> 4;
    long mbase = (long)blockIdx.x * 64;

    f32x4 acc[4][4];
#pragma unroll
    for (int mi = 0; mi < 4; ++mi)
#pragma unroll
        for (int ni = 0; ni < 4; ++ni) acc[mi][ni] = (f32x4){0.f, 0.f, 0.f, 0.f};

    for (int k0 = 0; k0 < KT; k0 += 64) {
        // stage A: 64 rows x 64 k, two passes of 32 rows
#pragma unroll
        for (int p = 0; p < 2; ++p) {
            int r = p * 32 + (tid >> 3);
            int c8 = tid & 7;
            long row = mbase + r;
            short8 val = {0, 0, 0, 0, 0, 0, 0, 0};
            if (row < N_NODES_C) {
                if (SRCF32) {
                    const float* Xf = (const float*)Xv;
                    const f32x4* p4 = (const f32x4*)&Xf[row * KT + k0 + c8 * 8];
                    f32x4 a0 = p4[0], a1 = p4[1];
#pragma unroll
                    for (int q = 0; q < 4; ++q) val[q] = (short)f2b(a0[q]);
#pragma unroll
                    for (int q = 0; q < 4; ++q) val[4 + q] = (short)f2b(a1[q]);
                } else {
                    const unsigned short* Xb = (const unsigned short*)Xv;
                    val = *(const short8*)&Xb[row * KT + k0 + c8 * 8];
                }
            }
            *(short8*)&As[r * 64 + ((c8 ^ (r & 7)) * 8)] = val;
        }
        // stage B: thread t = output col n, reads 64 k values (8x16B)
        {
            int n = tid;
#pragma unroll
            for (int c8 = 0; c8 < 8; ++c8) {
                *(short8*)&Bs[n * 64 + ((c8 ^ (n & 7)) * 8)] =
                    *(const short8*)&Wt[(long)n * KT + k0 + c8 * 8];
            }
        }
        __syncthreads();
#pragma unroll
        for (int kk = 0; kk < 2; ++kk) {
            int cblk = kk * 4 + lg;
            short8 a[4], b[4];
#pragma unroll
            for (int mi = 0; mi < 4; ++mi) {
                int R = mi * 16 + lr;
                a[mi] = *(const short8*)&As[R * 64 + ((cblk ^ (R & 7)) * 8)];
            }
#pragma unroll
            for (int ni = 0; ni < 4; ++ni) {
                int Nr = w * 64 + ni * 16 + lr;
                b[ni] = *(const short8*)&Bs[Nr * 64 + ((cblk ^ (Nr & 7)) * 8)];
            }
#pragma unroll
            for (int mi = 0; mi < 4; ++mi)
#pragma unroll
                for (int ni = 0; ni < 4; ++ni)
                    acc[mi][ni] = __builtin_amdgcn_mfma_f32_16x16x32_bf16(a[mi], b[ni],
                                                                          acc[mi][ni], 0, 0, 0);
        }
        __syncthreads();
    }
    // epilogue: D row = mi*16 + lg*4 + r, col = w*64 + ni*16 + lr
#pragma unroll
    for (int mi = 0; mi < 4; ++mi) {
#pragma unroll
        for (int r = 0; r < 4; ++r) {
            long row = mbase + mi * 16 + lg * 4 + r;
            if (row < N_NODES_C) {
#pragma unroll
                for (int ni = 0; ni < 4; ++ni) {
                    H[row * HID_C + w * 64 + ni * 16 + lr] = f2b(acc[mi][ni][r]);
                }
            }
        }
    }
}

// ---------------- per-node dots (bf16 H): 8 nodes per block ----------------
__global__ void k_dots(const unsigned short* __restrict__ H, const float* __restrict__ att_s,
                       const float* __restrict__ att_d, float* __restrict__ asrc,
                       float* __restrict__ adst) {
    int tid = threadIdx.x;
    int w = tid >> 6, l = tid & 63, sub = l >> 5;
    int node = blockIdx.x * 8 + w * 2 + sub;
    if (node >= N_NODES_C) return;
    int c8 = (l & 31) * 8;
    short8 hv = *(const short8*)&H[(long)node * HID_C + c8];
    const f32x4* as4 = (const f32x4*)&att_s[c8];
    const f32x4* ad4 = (const f32x4*)&att_d[c8];
    f32x4 s0 = as4[0], s1 = as4[1], d0 = ad4[0], d1 = ad4[1];
    float s = 0.f, d = 0.f;
#pragma unroll
    for (int q = 0; q < 4; ++q) {
        float h = b2f((unsigned short)hv[q]);
        s += h * s0[q];
        d += h * d0[q];
    }
#pragma unroll
    for (int q = 0; q < 4; ++q) {
        float h = b2f((unsigned short)hv[4 + q]);
        s += h * s1[q];
        d += h * d1[q];
    }
    for (int off = 16; off > 0; off >>= 1) {
        s += __shfl_down(s, off, 32);
        d += __shfl_down(d, off, 32);
    }
    if ((l & 31) == 0) {
        asrc[node] = s;
        adst[node] = d;
    }
}

// ---------------- per-dst softmax (no max-pass) + weighted bf16 aggregation ----------------
// Phase C: 8 edges in flight (4 waves x 2 half-waves), 16B/lane, unroll x2.
__global__ __launch_bounds__(256) void k_aggr(const int* __restrict__ offs,
                                              const int* __restrict__ ssrc,
                                              const float* __restrict__ sae,
                                              const float* __restrict__ asrc,
                                              const float* __restrict__ adst,
                                              const unsigned short* __restrict__ H,
                                              const float* __restrict__ bias,
                                              void* __restrict__ outp, int mode) {
    __shared__ float red[256];
    __shared__ float wts[MAXDEG];
    __shared__ float pacc[8][HID_C];
    int i = blockIdx.x;
    int tid = threadIdx.x;
    int off0 = offs[i];
    int deg = offs[i + 1] - off0;
    float adi = adst[i];

    // exp + block sum (no max subtraction: logits are O(1))
    float lsum = 0.f;
    for (int j = tid; j < deg; j += 256) {
        float a = asrc[ssrc[off0 + j]] + adi + sae[off0 + j];
        a = (a > 0.f) ? a : NEG_SLOPE_C * a;
        float ex = __expf(a);
        if (j < MAXDEG) wts[j] = ex;
        lsum += ex;
    }
    red[tid] = lsum;
    __syncthreads();
    for (int s = 128; s > 0; s >>= 1) {
        if (tid < s) red[tid] += red[tid + s];
        __syncthreads();
    }
    float inv = 1.0f / (red[0] + 1e-16f);

    auto getw = [&](int j) -> float {
        if (j < MAXDEG) return wts[j];
        float a = asrc[ssrc[off0 + j]] + adi + sae[off0 + j];
        a = (a > 0.f) ? a : NEG_SLOPE_C * a;
        return __expf(a);
    };

    int w = tid >> 6, l = tid & 63, sub = l >> 5;
    int c8 = (l & 31) * 8;
    float acc[8];
#pragma unroll
    for (int q = 0; q < 8; ++q) acc[q] = 0.f;

    int j = w * 2 + sub;
    for (; j + 8 < deg; j += 16) {
        int s0 = ssrc[off0 + j];
        int s1 = ssrc[off0 + j + 8];
        float w0 = getw(j);
        float w1 = getw(j + 8);
        short8 h0 = *(const short8*)&H[(long)s0 * HID_C + c8];
        short8 h1 = *(const short8*)&H[(long)s1 * HID_C + c8];
#pragma unroll
        for (int q = 0; q < 8; ++q)
            acc[q] += w0 * b2f((unsigned short)h0[q]) + w1 * b2f((unsigned short)h1[q]);
    }
    if (j < deg) {
        int s0 = ssrc[off0 + j];
        float w0 = getw(j);
        short8 h0 = *(const short8*)&H[(long)s0 * HID_C + c8];
#pragma unroll
        for (int q = 0; q < 8; ++q) acc[q] += w0 * b2f((unsigned short)h0[q]);
    }
    f32x4 p0 = {acc[0], acc[1], acc[2], acc[3]};
    f32x4 p1 = {acc[4], acc[5], acc[6], acc[7]};
    *(f32x4*)&pacc[w * 2 + sub][c8] = p0;
    *(f32x4*)&pacc[w * 2 + sub][c8 + 4] = p1;
    __syncthreads();

    float r = 0.f;
#pragma unroll
    for (int q = 0; q < 8; ++q) r += pacc[q][tid];
    r = r * inv + bias[tid];
    if (mode == 1) {
        r = fmaxf(r, 0.f);
        ((unsigned short*)outp)[(long)i * HID_C + tid] = f2b(r);
    } else {
        ((float*)outp)[(long)i * HID_C + tid] = r;
    }
}

extern "C" void kernel_launch(void* const* d_in, const int* in_sizes, int n_in,
                              void* d_out, int out_size, void* d_ws, size_t ws_size,
                              hipStream_t stream) {
    const float* x     = (const float*)d_in[0];
    const int*   ei    = (const int*)d_in[1];     // [2, E]: row0=src, row1=dst
    const float* eattr = (const float*)d_in[2];
    const float* W1    = (const float*)d_in[3];
    const float* atts1 = (const float*)d_in[4];
    const float* attd1 = (const float*)d_in[5];
    const float* We1   = (const float*)d_in[6];
    const float* atte1 = (const float*)d_in[7];
    const float* b1    = (const float*)d_in[8];
    const float* W2    = (const float*)d_in[9];
    const float* atts2 = (const float*)d_in[10];
    const float* attd2 = (const float*)d_in[11];
    const float* We2   = (const float*)d_in[12];
    const float* atte2 = (const float*)d_in[13];
    const float* b2    = (const float*)d_in[14];
    float* out = (float*)d_out;

    char* ws = (char*)d_ws;
    size_t off = 0;
    auto alloc = [&](size_t bytes) -> void* {
        void* p = ws + off;
        off = (off + bytes + 255) & ~(size_t)255;
        return p;
    };
    int*   deg  = (int*)alloc((size_t)N_NODES_C * 4);
    int*   offs = (int*)alloc(((size_t)N_NODES_C + 1) * 4);
    int*   cur  = (int*)alloc((size_t)N_NODES_C * 4);
    int*   ssrc = (int*)alloc((size_t)N_EDGES_C * 4);
    float* sae1 = (float*)alloc((size_t)N_EDGES_C * 4);
    float* sae2 = (float*)alloc((size_t)N_EDGES_C * 4);
    float* asrc = (float*)alloc((size_t)N_NODES_C * 4);
    float* adst = (float*)alloc((size_t)N_NODES_C * 4);
    float* v    = (float*)alloc(64);
    unsigned short* W1t = (unsigned short*)alloc((size_t)HID_C * IN_DIM_C * 2);
    unsigned short* W2t = (unsigned short*)alloc((size_t)HID_C * HID_C * 2);
    unsigned short* h1  = (unsigned short*)alloc((size_t)N_NODES_C * HID_C * 2);  // also h2
    unsigned short* g1  = (unsigned short*)alloc((size_t)N_NODES_C * HID_C * 2);

    const int* src = ei;
    const int* dst = ei + N_EDGES_C;

    hipMemsetAsync(deg, 0, (size_t)N_NODES_C * 4, stream);
    hipMemsetAsync(cur, 0, (size_t)N_NODES_C * 4, stream);

    k_prep<<<HID_C * HID_C / 256, 256, 0, stream>>>(W1, W2, W1t, W2t);
    k_v12<<<1, 256, 0, stream>>>(We1, atte1, We2, atte2, v);
    k_hist<<<1024, 256, 0, stream>>>(dst, deg);
    k_scan<<<1, 1024, 0, stream>>>(deg, offs);
    k_scatter<<<1024, 256, 0, stream>>>(src, dst, eattr, offs, cur, v, ssrc, sae1, sae2);

    int gemm_grid = (N_NODES_C + 63) / 64;
    // layer 1
    k_gemm_mfma<IN_DIM_C, true><<<gemm_grid, 256, 0, stream>>>(x, W1t, h1);
    k_dots<<<N_NODES_C / 8, 256, 0, stream>>>(h1, atts1, attd1, asrc, adst);
    k_aggr<<<N_NODES_C, 256, 0, stream>>>(offs, ssrc, sae1, asrc, adst, h1, b1, g1, 1);
    // layer 2 (h2 aliases h1 buffer)
    k_gemm_mfma<HID_C, false><<<gemm_grid, 256, 0, stream>>>(g1, W2t, h1);
    k_dots<<<N_NODES_C / 8, 256, 0, stream>>>(h1, atts2, attd2, asrc, adst);
    k_aggr<<<N_NODES_C, 256, 0, stream>>>(offs, ssrc, sae2, asrc, adst, h1, b2, out, 0);
}

// Round 4
// 307.259 us; speedup vs baseline: 2.6891x; 1.2306x over previous
//
#include <hip/hip_runtime.h>
#include <hip/hip_bf16.h>

#define N_NODES_C 50000
#define N_EDGES_C 800000
#define IN_DIM_C 64
#define HID_C 256
#define EDGE_DIM_C 6
#define NEG_SLOPE_C 0.2f

typedef short short8 __attribute__((ext_vector_type(8)));
typedef float f32x4 __attribute__((ext_vector_type(4)));

static __device__ __forceinline__ float b2f(unsigned short u) {
    union { unsigned int i; float f; } x;
    x.i = ((unsigned int)u) << 16;
    return x.f;
}
static __device__ __forceinline__ unsigned short f2b(float f) {
    union { __hip_bfloat16 h; unsigned short u; } x;
    x.h = __float2bfloat16(f);
    return x.u;
}

// ---------------- prep: W1 [64,256] -> W1t bf16 [256][64]; W2 [256,256] -> W2t bf16 [256][256]
__global__ void k_prep(const float* __restrict__ W1, const float* __restrict__ W2,
                       unsigned short* __restrict__ W1t, unsigned short* __restrict__ W2t) {
    int i = blockIdx.x * blockDim.x + threadIdx.x;
    if (i < IN_DIM_C * HID_C) {
        int k = i >> 8, n = i & 255;
        W1t[n * IN_DIM_C + k] = f2b(W1[i]);
    }
    if (i < HID_C * HID_C) {
        int k = i >> 8, n = i & 255;
        W2t[n * HID_C + k] = f2b(W2[i]);
    }
}

// ---------------- v = We @ att_e (6 scalars per layer) ----------------
__global__ void k_v12(const float* __restrict__ We1, const float* __restrict__ atte1,
                      const float* __restrict__ We2, const float* __restrict__ atte2,
                      float* __restrict__ v) {
    __shared__ float red[256];
    int tid = threadIdx.x;
    for (int layer = 0; layer < 2; ++layer) {
        const float* We = layer ? We2 : We1;
        const float* ae = layer ? atte2 : atte1;
        for (int k = 0; k < EDGE_DIM_C; ++k) {
            red[tid] = We[k * HID_C + tid] * ae[tid];
            __syncthreads();
            for (int s = 128; s > 0; s >>= 1) {
                if (tid < s) red[tid] += red[tid + s];
                __syncthreads();
            }
            if (tid == 0) v[layer * 8 + k] = red[0];
            __syncthreads();
        }
    }
}

// ---------------- degree histogram over dst ----------------
__global__ void k_hist(const int* __restrict__ dst, int* __restrict__ deg) {
    int e = blockIdx.x * blockDim.x + threadIdx.x;
    if (e < N_EDGES_C) atomicAdd(&deg[dst[e]], 1);
}

// ---------------- two-level scan ----------------
__global__ void k_scan1(const int* __restrict__ deg, int* __restrict__ offs,
                        int* __restrict__ bsum) {
    __shared__ int tmp[256];
    int b = blockIdx.x, tid = threadIdx.x;
    int i = b * 256 + tid;
    int v = (i < N_NODES_C) ? deg[i] : 0;
    tmp[tid] = v;
    __syncthreads();
    for (int d = 1; d < 256; d <<= 1) {
        int t = (tid >= d) ? tmp[tid - d] : 0;
        __syncthreads();
        tmp[tid] += t;
        __syncthreads();
    }
    if (i < N_NODES_C) offs[i] = tmp[tid] - v;  // exclusive within block
    if (tid == 255) bsum[b] = tmp[255];
}
__global__ void k_scan2(const int* __restrict__ bsum, int* __restrict__ boff, int nb) {
    __shared__ int tmp[256];
    int tid = threadIdx.x;
    int v = (tid < nb) ? bsum[tid] : 0;
    tmp[tid] = v;
    __syncthreads();
    for (int d = 1; d < 256; d <<= 1) {
        int t = (tid >= d) ? tmp[tid - d] : 0;
        __syncthreads();
        tmp[tid] += t;
        __syncthreads();
    }
    if (tid < nb) boff[tid] = tmp[tid] - v;
}
__global__ void k_scan3(int* __restrict__ offs, const int* __restrict__ boff) {
    int b = blockIdx.x, tid = threadIdx.x;
    int i = b * 256 + tid;
    if (i < N_NODES_C) offs[i] += boff[b];
    if (i == 0) offs[N_NODES_C] = N_EDGES_C;
}

// ---------------- scatter edges into CSR order + per-edge a_edge ----------------
__global__ void k_scatter(const int* __restrict__ src, const int* __restrict__ dst,
                          const float* __restrict__ eattr, const int* __restrict__ offs,
                          int* __restrict__ cur, const float* __restrict__ v,
                          int* __restrict__ ssrc, int* __restrict__ sdst,
                          float* __restrict__ sae1, float* __restrict__ sae2) {
    int e = blockIdx.x * blockDim.x + threadIdx.x;
    if (e >= N_EDGES_C) return;
    int d = dst[e];
    int pos = offs[d] + atomicAdd(&cur[d], 1);
    ssrc[pos] = src[e];
    sdst[pos] = d;
    float a1 = 0.f, a2 = 0.f;
#pragma unroll
    for (int k = 0; k < EDGE_DIM_C; ++k) {
        float ea = eattr[e * EDGE_DIM_C + k];
        a1 += ea * v[k];
        a2 += ea * v[8 + k];
    }
    sae1[pos] = a1;
    sae2[pos] = a2;
}

// ---------------- MFMA GEMM: H[M,256] = X[M,KT] @ Wt^T  (Wt is [256 n][KT k] bf16)
template <int KT, bool SRCF32>
__global__ __launch_bounds__(256) void k_gemm_mfma(const void* __restrict__ Xv,
                                                   const unsigned short* __restrict__ Wt,
                                                   unsigned short* __restrict__ H) {
    __shared__ unsigned short As[64 * 64];   // 8 KB
    __shared__ unsigned short Bs[256 * 64];  // 32 KB
    int tid = threadIdx.x;
    int w = tid >> 6, l = tid & 63;
    int lr = l & 15, lg = l >> 4;
    long mbase = (long)blockIdx.x * 64;

    f32x4 acc[4][4];
#pragma unroll
    for (int mi = 0; mi < 4; ++mi)
#pragma unroll
        for (int ni = 0; ni < 4; ++ni) acc[mi][ni] = (f32x4){0.f, 0.f, 0.f, 0.f};

    for (int k0 = 0; k0 < KT; k0 += 64) {
#pragma unroll
        for (int p = 0; p < 2; ++p) {
            int r = p * 32 + (tid >> 3);
            int c8 = tid & 7;
            long row = mbase + r;
            short8 val = {0, 0, 0, 0, 0, 0, 0, 0};
            if (row < N_NODES_C) {
                if (SRCF32) {
                    const float* Xf = (const float*)Xv;
                    const f32x4* p4 = (const f32x4*)&Xf[row * KT + k0 + c8 * 8];
                    f32x4 a0 = p4[0], a1 = p4[1];
#pragma unroll
                    for (int q = 0; q < 4; ++q) val[q] = (short)f2b(a0[q]);
#pragma unroll
                    for (int q = 0; q < 4; ++q) val[4 + q] = (short)f2b(a1[q]);
                } else {
                    const unsigned short* Xb = (const unsigned short*)Xv;
                    val = *(const short8*)&Xb[row * KT + k0 + c8 * 8];
                }
            }
            *(short8*)&As[r * 64 + ((c8 ^ (r & 7)) * 8)] = val;
        }
        {
            int n = tid;
#pragma unroll
            for (int c8 = 0; c8 < 8; ++c8) {
                *(short8*)&Bs[n * 64 + ((c8 ^ (n & 7)) * 8)] =
                    *(const short8*)&Wt[(long)n * KT + k0 + c8 * 8];
            }
        }
        __syncthreads();
#pragma unroll
        for (int kk = 0; kk < 2; ++kk) {
            int cblk = kk * 4 + lg;
            short8 a[4], b[4];
#pragma unroll
            for (int mi = 0; mi < 4; ++mi) {
                int R = mi * 16 + lr;
                a[mi] = *(const short8*)&As[R * 64 + ((cblk ^ (R & 7)) * 8)];
            }
#pragma unroll
            for (int ni = 0; ni < 4; ++ni) {
                int Nr = w * 64 + ni * 16 + lr;
                b[ni] = *(const short8*)&Bs[Nr * 64 + ((cblk ^ (Nr & 7)) * 8)];
            }
#pragma unroll
            for (int mi = 0; mi < 4; ++mi)
#pragma unroll
                for (int ni = 0; ni < 4; ++ni)
                    acc[mi][ni] = __builtin_amdgcn_mfma_f32_16x16x32_bf16(a[mi], b[ni],
                                                                          acc[mi][ni], 0, 0, 0);
        }
        __syncthreads();
    }
#pragma unroll
    for (int mi = 0; mi < 4; ++mi) {
#pragma unroll
        for (int r = 0; r < 4; ++r) {
            long row = mbase + mi * 16 + lg * 4 + r;
            if (row < N_NODES_C) {
#pragma unroll
                for (int ni = 0; ni < 4; ++ni) {
                    H[row * HID_C + w * 64 + ni * 16 + lr] = f2b(acc[mi][ni][r]);
                }
            }
        }
    }
}

// ---------------- per-node dots (bf16 H): 8 nodes per block ----------------
__global__ void k_dots(const unsigned short* __restrict__ H, const float* __restrict__ att_s,
                       const float* __restrict__ att_d, float* __restrict__ asrc,
                       float* __restrict__ adst) {
    int tid = threadIdx.x;
    int w = tid >> 6, l = tid & 63, sub = l >> 5;
    int node = blockIdx.x * 8 + w * 2 + sub;
    if (node >= N_NODES_C) return;
    int c8 = (l & 31) * 8;
    short8 hv = *(const short8*)&H[(long)node * HID_C + c8];
    const f32x4* as4 = (const f32x4*)&att_s[c8];
    const f32x4* ad4 = (const f32x4*)&att_d[c8];
    f32x4 s0 = as4[0], s1 = as4[1], d0 = ad4[0], d1 = ad4[1];
    float s = 0.f, d = 0.f;
#pragma unroll
    for (int q = 0; q < 4; ++q) {
        float h = b2f((unsigned short)hv[q]);
        s += h * s0[q];
        d += h * d0[q];
    }
#pragma unroll
    for (int q = 0; q < 4; ++q) {
        float h = b2f((unsigned short)hv[4 + q]);
        s += h * s1[q];
        d += h * d1[q];
    }
    for (int off = 16; off > 0; off >>= 1) {
        s += __shfl_down(s, off, 32);
        d += __shfl_down(d, off, 32);
    }
    if ((l & 31) == 0) {
        asrc[node] = s;
        adst[node] = d;
    }
}

// ---------------- edge-parallel unnormalized softmax weights ----------------
__global__ void k_wts(const int* __restrict__ ssrc, const int* __restrict__ sdst,
                      const float* __restrict__ sae, const float* __restrict__ asrc,
                      const float* __restrict__ adst, float* __restrict__ wts) {
    int p = blockIdx.x * blockDim.x + threadIdx.x;
    if (p >= N_EDGES_C) return;
    float a = asrc[ssrc[p]] + adst[sdst[p]] + sae[p];
    a = (a > 0.f) ? a : NEG_SLOPE_C * a;
    wts[p] = __expf(a);
}

// ---------------- halfwave-per-node weighted aggregation (no LDS, no barriers) ----------------
__global__ __launch_bounds__(256) void k_aggr2(const int* __restrict__ offs,
                                               const int* __restrict__ ssrc,
                                               const float* __restrict__ wts,
                                               const unsigned short* __restrict__ H,
                                               const float* __restrict__ bias,
                                               void* __restrict__ outp, int mode) {
    int tid = threadIdx.x;
    int hw = tid >> 5;      // halfwave 0..7
    int l = tid & 31;
    int node = blockIdx.x * 8 + hw;
    if (node >= N_NODES_C) return;
    int off0 = offs[node];
    int deg = offs[node + 1] - off0;

    // denom: lane-strided sum over wts, butterfly within 32 lanes
    float s = 0.f;
    for (int j = l; j < deg; j += 32) s += wts[off0 + j];
#pragma unroll
    for (int o = 16; o > 0; o >>= 1) s += __shfl_xor(s, o, 32);
    float inv = 1.0f / (s + 1e-16f);

    int c8 = l * 8;
    float acc[8];
#pragma unroll
    for (int q = 0; q < 8; ++q) acc[q] = 0.f;

    int j = 0;
    for (; j + 1 < deg; j += 2) {
        int s0 = ssrc[off0 + j];
        int s1 = ssrc[off0 + j + 1];
        float w0 = wts[off0 + j];
        float w1 = wts[off0 + j + 1];
        short8 h0 = *(const short8*)&H[(long)s0 * HID_C + c8];
        short8 h1 = *(const short8*)&H[(long)s1 * HID_C + c8];
#pragma unroll
        for (int q = 0; q < 8; ++q)
            acc[q] += w0 * b2f((unsigned short)h0[q]) + w1 * b2f((unsigned short)h1[q]);
    }
    if (j < deg) {
        int s0 = ssrc[off0 + j];
        float w0 = wts[off0 + j];
        short8 h0 = *(const short8*)&H[(long)s0 * HID_C + c8];
#pragma unroll
        for (int q = 0; q < 8; ++q) acc[q] += w0 * b2f((unsigned short)h0[q]);
    }

    const f32x4* b4 = (const f32x4*)&bias[c8];
    f32x4 bv0 = b4[0], bv1 = b4[1];
    if (mode == 1) {
        unsigned short* o16 = (unsigned short*)outp;
        short8 r;
#pragma unroll
        for (int q = 0; q < 4; ++q)
            r[q] = (short)f2b(fmaxf(acc[q] * inv + bv0[q], 0.f));
#pragma unroll
        for (int q = 0; q < 4; ++q)
            r[4 + q] = (short)f2b(fmaxf(acc[4 + q] * inv + bv1[q], 0.f));
        *(short8*)&o16[(long)node * HID_C + c8] = r;
    } else {
        float* o32 = (float*)outp;
        f32x4 r0, r1;
#pragma unroll
        for (int q = 0; q < 4; ++q) r0[q] = acc[q] * inv + bv0[q];
#pragma unroll
        for (int q = 0; q < 4; ++q) r1[q] = acc[4 + q] * inv + bv1[q];
        *(f32x4*)&o32[(long)node * HID_C + c8] = r0;
        *(f32x4*)&o32[(long)node * HID_C + c8 + 4] = r1;
    }
}

extern "C" void kernel_launch(void* const* d_in, const int* in_sizes, int n_in,
                              void* d_out, int out_size, void* d_ws, size_t ws_size,
                              hipStream_t stream) {
    const float* x     = (const float*)d_in[0];
    const int*   ei    = (const int*)d_in[1];     // [2, E]: row0=src, row1=dst
    const float* eattr = (const float*)d_in[2];
    const float* W1    = (const float*)d_in[3];
    const float* atts1 = (const float*)d_in[4];
    const float* attd1 = (const float*)d_in[5];
    const float* We1   = (const float*)d_in[6];
    const float* atte1 = (const float*)d_in[7];
    const float* b1    = (const float*)d_in[8];
    const float* W2    = (const float*)d_in[9];
    const float* atts2 = (const float*)d_in[10];
    const float* attd2 = (const float*)d_in[11];
    const float* We2   = (const float*)d_in[12];
    const float* atte2 = (const float*)d_in[13];
    const float* b2    = (const float*)d_in[14];
    float* out = (float*)d_out;

    char* ws = (char*)d_ws;
    size_t off = 0;
    auto alloc = [&](size_t bytes) -> void* {
        void* p = ws + off;
        off = (off + bytes + 255) & ~(size_t)255;
        return p;
    };
    int*   deg  = (int*)alloc((size_t)N_NODES_C * 4);
    int*   offs = (int*)alloc(((size_t)N_NODES_C + 1) * 4);
    int*   cur  = (int*)alloc((size_t)N_NODES_C * 4);
    int*   ssrc = (int*)alloc((size_t)N_EDGES_C * 4);
    int*   sdst = (int*)alloc((size_t)N_EDGES_C * 4);
    float* sae1 = (float*)alloc((size_t)N_EDGES_C * 4);
    float* sae2 = (float*)alloc((size_t)N_EDGES_C * 4);
    float* wts  = (float*)alloc((size_t)N_EDGES_C * 4);
    float* asrc = (float*)alloc((size_t)N_NODES_C * 4);
    float* adst = (float*)alloc((size_t)N_NODES_C * 4);
    float* v    = (float*)alloc(64);
    int*   bsum = (int*)alloc(256 * 4);
    int*   boff = (int*)alloc(257 * 4);
    unsigned short* W1t = (unsigned short*)alloc((size_t)HID_C * IN_DIM_C * 2);
    unsigned short* W2t = (unsigned short*)alloc((size_t)HID_C * HID_C * 2);
    unsigned short* h1  = (unsigned short*)alloc((size_t)N_NODES_C * HID_C * 2);  // also h2
    unsigned short* g1  = (unsigned short*)alloc((size_t)N_NODES_C * HID_C * 2);

    const int* src = ei;
    const int* dst = ei + N_EDGES_C;
    int nb = (N_NODES_C + 255) / 256;  // 196

    hipMemsetAsync(deg, 0, (size_t)N_NODES_C * 4, stream);
    hipMemsetAsync(cur, 0, (size_t)N_NODES_C * 4, stream);

    k_prep<<<HID_C * HID_C / 256, 256, 0, stream>>>(W1, W2, W1t, W2t);
    k_v12<<<1, 256, 0, stream>>>(We1, atte1, We2, atte2, v);
    k_hist<<<(N_EDGES_C + 255) / 256, 256, 0, stream>>>(dst, deg);
    k_scan1<<<nb, 256, 0, stream>>>(deg, offs, bsum);
    k_scan2<<<1, 256, 0, stream>>>(bsum, boff, nb);
    k_scan3<<<nb, 256, 0, stream>>>(offs, boff);
    k_scatter<<<(N_EDGES_C + 255) / 256, 256, 0, stream>>>(src, dst, eattr, offs, cur, v,
                                                           ssrc, sdst, sae1, sae2);

    int gemm_grid = (N_NODES_C + 63) / 64;
    // layer 1
    k_gemm_mfma<IN_DIM_C, true><<<gemm_grid, 256, 0, stream>>>(x, W1t, h1);
    k_dots<<<N_NODES_C / 8, 256, 0, stream>>>(h1, atts1, attd1, asrc, adst);
    k_wts<<<(N_EDGES_C + 255) / 256, 256, 0, stream>>>(ssrc, sdst, sae1, asrc, adst, wts);
    k_aggr2<<<N_NODES_C / 8, 256, 0, stream>>>(offs, ssrc, wts, h1, b1, g1, 1);
    // layer 2 (h2 aliases h1 buffer)
    k_gemm_mfma<HID_C, false><<<gemm_grid, 256, 0, stream>>>(g1, W2t, h1);
    k_dots<<<N_NODES_C / 8, 256, 0, stream>>>(h1, atts2, attd2, asrc, adst);
    k_wts<<<(N_EDGES_C + 255) / 256, 256, 0, stream>>>(ssrc, sdst, sae2, asrc, adst, wts);
    k_aggr2<<<N_NODES_C / 8, 256, 0, stream>>>(offs, ssrc, wts, h1, b2, out, 0);
}

// Round 5
// 304.706 us; speedup vs baseline: 2.7117x; 1.0084x over previous
//
#include <hip/hip_runtime.h>
#include <hip/hip_bf16.h>

#define N_NODES_C 50000
#define N_EDGES_C 800000
#define IN_DIM_C 64
#define HID_C 256
#define EDGE_DIM_C 6
#define NEG_SLOPE_C 0.2f

typedef short short8 __attribute__((ext_vector_type(8)));
typedef float f32x4 __attribute__((ext_vector_type(4)));

static __device__ __forceinline__ float b2f(unsigned short u) {
    union { unsigned int i; float f; } x;
    x.i = ((unsigned int)u) << 16;
    return x.f;
}
static __device__ __forceinline__ unsigned short f2b(float f) {
    union { __hip_bfloat16 h; unsigned short u; } x;
    x.h = __float2bfloat16(f);
    return x.u;
}

// ---------------- prep: W1 [64,256] -> W1t bf16 [256][64]; W2 [256,256] -> W2t bf16 [256][256]
__global__ void k_prep(const float* __restrict__ W1, const float* __restrict__ W2,
                       unsigned short* __restrict__ W1t, unsigned short* __restrict__ W2t) {
    int i = blockIdx.x * blockDim.x + threadIdx.x;
    if (i < IN_DIM_C * HID_C) {
        int k = i >> 8, n = i & 255;
        W1t[n * IN_DIM_C + k] = f2b(W1[i]);
    }
    if (i < HID_C * HID_C) {
        int k = i >> 8, n = i & 255;
        W2t[n * HID_C + k] = f2b(W2[i]);
    }
}

// ---------------- v = We @ att_e (6 scalars per layer) ----------------
__global__ void k_v12(const float* __restrict__ We1, const float* __restrict__ atte1,
                      const float* __restrict__ We2, const float* __restrict__ atte2,
                      float* __restrict__ v) {
    __shared__ float red[256];
    int tid = threadIdx.x;
    for (int layer = 0; layer < 2; ++layer) {
        const float* We = layer ? We2 : We1;
        const float* ae = layer ? atte2 : atte1;
        for (int k = 0; k < EDGE_DIM_C; ++k) {
            red[tid] = We[k * HID_C + tid] * ae[tid];
            __syncthreads();
            for (int s = 128; s > 0; s >>= 1) {
                if (tid < s) red[tid] += red[tid + s];
                __syncthreads();
            }
            if (tid == 0) v[layer * 8 + k] = red[0];
            __syncthreads();
        }
    }
}

// ---------------- degree histogram over dst ----------------
__global__ void k_hist(const int* __restrict__ dst, int* __restrict__ deg) {
    int e = blockIdx.x * blockDim.x + threadIdx.x;
    if (e < N_EDGES_C) atomicAdd(&deg[dst[e]], 1);
}

// ---------------- two-level scan ----------------
__global__ void k_scan1(const int* __restrict__ deg, int* __restrict__ offs,
                        int* __restrict__ bsum) {
    __shared__ int tmp[256];
    int b = blockIdx.x, tid = threadIdx.x;
    int i = b * 256 + tid;
    int v = (i < N_NODES_C) ? deg[i] : 0;
    tmp[tid] = v;
    __syncthreads();
    for (int d = 1; d < 256; d <<= 1) {
        int t = (tid >= d) ? tmp[tid - d] : 0;
        __syncthreads();
        tmp[tid] += t;
        __syncthreads();
    }
    if (i < N_NODES_C) offs[i] = tmp[tid] - v;  // exclusive within block
    if (tid == 255) bsum[b] = tmp[255];
}
__global__ void k_scan2(const int* __restrict__ bsum, int* __restrict__ boff, int nb) {
    __shared__ int tmp[256];
    int tid = threadIdx.x;
    int v = (tid < nb) ? bsum[tid] : 0;
    tmp[tid] = v;
    __syncthreads();
    for (int d = 1; d < 256; d <<= 1) {
        int t = (tid >= d) ? tmp[tid - d] : 0;
        __syncthreads();
        tmp[tid] += t;
        __syncthreads();
    }
    if (tid < nb) boff[tid] = tmp[tid] - v;
}
__global__ void k_scan3(int* __restrict__ offs, const int* __restrict__ boff) {
    int b = blockIdx.x, tid = threadIdx.x;
    int i = b * 256 + tid;
    if (i < N_NODES_C) offs[i] += boff[b];
    if (i == 0) offs[N_NODES_C] = N_EDGES_C;
}

// ---------------- perm build: single random 4B write per edge ----------------
// cur is pre-initialized (d2d copy) to offs, so atomicAdd yields the global slot.
__global__ void k_perm(const int* __restrict__ dst, int* __restrict__ cur,
                       int* __restrict__ perm) {
    int e = blockIdx.x * blockDim.x + threadIdx.x;
    if (e >= N_EDGES_C) return;
    int pos = atomicAdd(&cur[dst[e]], 1);
    perm[pos] = e;
}

// ---------------- CSR materialization: coalesced writes, random reads (L3) ----------------
__global__ void k_gather(const int* __restrict__ perm, const int* __restrict__ src,
                         const float* __restrict__ eattr, const float* __restrict__ v,
                         int* __restrict__ ssrc, float* __restrict__ sae1,
                         float* __restrict__ sae2) {
    int p = blockIdx.x * blockDim.x + threadIdx.x;
    if (p >= N_EDGES_C) return;
    int e = perm[p];
    ssrc[p] = src[e];
    float a1 = 0.f, a2 = 0.f;
#pragma unroll
    for (int k = 0; k < EDGE_DIM_C; ++k) {
        float ea = eattr[e * EDGE_DIM_C + k];
        a1 += ea * v[k];
        a2 += ea * v[8 + k];
    }
    sae1[p] = a1;
    sae2[p] = a2;
}

// ---------------- MFMA GEMM: H[M,256] = X[M,KT] @ Wt^T  (Wt is [256 n][KT k] bf16)
template <int KT, bool SRCF32>
__global__ __launch_bounds__(256) void k_gemm_mfma(const void* __restrict__ Xv,
                                                   const unsigned short* __restrict__ Wt,
                                                   unsigned short* __restrict__ H) {
    __shared__ unsigned short As[64 * 64];   // 8 KB
    __shared__ unsigned short Bs[256 * 64];  // 32 KB
    int tid = threadIdx.x;
    int w = tid >> 6, l = tid & 63;
    int lr = l & 15, lg = l >> 4;
    long mbase = (long)blockIdx.x * 64;

    f32x4 acc[4][4];
#pragma unroll
    for (int mi = 0; mi < 4; ++mi)
#pragma unroll
        for (int ni = 0; ni < 4; ++ni) acc[mi][ni] = (f32x4){0.f, 0.f, 0.f, 0.f};

    for (int k0 = 0; k0 < KT; k0 += 64) {
#pragma unroll
        for (int p = 0; p < 2; ++p) {
            int r = p * 32 + (tid >> 3);
            int c8 = tid & 7;
            long row = mbase + r;
            short8 val = {0, 0, 0, 0, 0, 0, 0, 0};
            if (row < N_NODES_C) {
                if (SRCF32) {
                    const float* Xf = (const float*)Xv;
                    const f32x4* p4 = (const f32x4*)&Xf[row * KT + k0 + c8 * 8];
                    f32x4 a0 = p4[0], a1 = p4[1];
#pragma unroll
                    for (int q = 0; q < 4; ++q) val[q] = (short)f2b(a0[q]);
#pragma unroll
                    for (int q = 0; q < 4; ++q) val[4 + q] = (short)f2b(a1[q]);
                } else {
                    const unsigned short* Xb = (const unsigned short*)Xv;
                    val = *(const short8*)&Xb[row * KT + k0 + c8 * 8];
                }
            }
            *(short8*)&As[r * 64 + ((c8 ^ (r & 7)) * 8)] = val;
        }
        {
            int n = tid;
#pragma unroll
            for (int c8 = 0; c8 < 8; ++c8) {
                *(short8*)&Bs[n * 64 + ((c8 ^ (n & 7)) * 8)] =
                    *(const short8*)&Wt[(long)n * KT + k0 + c8 * 8];
            }
        }
        __syncthreads();
#pragma unroll
        for (int kk = 0; kk < 2; ++kk) {
            int cblk = kk * 4 + lg;
            short8 a[4], b[4];
#pragma unroll
            for (int mi = 0; mi < 4; ++mi) {
                int R = mi * 16 + lr;
                a[mi] = *(const short8*)&As[R * 64 + ((cblk ^ (R & 7)) * 8)];
            }
#pragma unroll
            for (int ni = 0; ni < 4; ++ni) {
                int Nr = w * 64 + ni * 16 + lr;
                b[ni] = *(const short8*)&Bs[Nr * 64 + ((cblk ^ (Nr & 7)) * 8)];
            }
#pragma unroll
            for (int mi = 0; mi < 4; ++mi)
#pragma unroll
                for (int ni = 0; ni < 4; ++ni)
                    acc[mi][ni] = __builtin_amdgcn_mfma_f32_16x16x32_bf16(a[mi], b[ni],
                                                                          acc[mi][ni], 0, 0, 0);
        }
        __syncthreads();
    }
#pragma unroll
    for (int mi = 0; mi < 4; ++mi) {
#pragma unroll
        for (int r = 0; r < 4; ++r) {
            long row = mbase + mi * 16 + lg * 4 + r;
            if (row < N_NODES_C) {
#pragma unroll
                for (int ni = 0; ni < 4; ++ni) {
                    H[row * HID_C + w * 64 + ni * 16 + lr] = f2b(acc[mi][ni][r]);
                }
            }
        }
    }
}

// ---------------- per-node dots (bf16 H): 8 nodes per block ----------------
__global__ void k_dots(const unsigned short* __restrict__ H, const float* __restrict__ att_s,
                       const float* __restrict__ att_d, float* __restrict__ asrc,
                       float* __restrict__ adst) {
    int tid = threadIdx.x;
    int w = tid >> 6, l = tid & 63, sub = l >> 5;
    int node = blockIdx.x * 8 + w * 2 + sub;
    if (node >= N_NODES_C) return;
    int c8 = (l & 31) * 8;
    short8 hv = *(const short8*)&H[(long)node * HID_C + c8];
    const f32x4* as4 = (const f32x4*)&att_s[c8];
    const f32x4* ad4 = (const f32x4*)&att_d[c8];
    f32x4 s0 = as4[0], s1 = as4[1], d0 = ad4[0], d1 = ad4[1];
    float s = 0.f, d = 0.f;
#pragma unroll
    for (int q = 0; q < 4; ++q) {
        float h = b2f((unsigned short)hv[q]);
        s += h * s0[q];
        d += h * d0[q];
    }
#pragma unroll
    for (int q = 0; q < 4; ++q) {
        float h = b2f((unsigned short)hv[4 + q]);
        s += h * s1[q];
        d += h * d1[q];
    }
    for (int off = 16; off > 0; off >>= 1) {
        s += __shfl_down(s, off, 32);
        d += __shfl_down(d, off, 32);
    }
    if ((l & 31) == 0) {
        asrc[node] = s;
        adst[node] = d;
    }
}

// ---------------- halfwave-per-node: fused softmax weights + aggregation ----------------
// Lane l computes w for edges l and l+32 in registers (deg>64 is a cold tail);
// the gather loop broadcasts (src_idx, w) via shfl -> no edge reloads, 4 rows in flight.
__global__ __launch_bounds__(256) void k_aggr2(const int* __restrict__ offs,
                                               const int* __restrict__ ssrc,
                                               const float* __restrict__ sae,
                                               const float* __restrict__ asrc,
                                               const float* __restrict__ adst,
                                               const unsigned short* __restrict__ H,
                                               const float* __restrict__ bias,
                                               void* __restrict__ outp, int mode) {
    int tid = threadIdx.x;
    int hw = tid >> 5;
    int l = tid & 31;
    int node = blockIdx.x * 8 + hw;
    if (node >= N_NODES_C) return;
    int off0 = offs[node];
    int deg = offs[node + 1] - off0;
    float adi = adst[node];

    int sidx0 = 0, sidx1 = 0;
    float w0 = 0.f, w1 = 0.f;
    if (l < deg) {
        sidx0 = ssrc[off0 + l];
        float a = asrc[sidx0] + adi + sae[off0 + l];
        a = (a > 0.f) ? a : NEG_SLOPE_C * a;
        w0 = __expf(a);
    }
    if (32 + l < deg) {
        sidx1 = ssrc[off0 + 32 + l];
        float a = asrc[sidx1] + adi + sae[off0 + 32 + l];
        a = (a > 0.f) ? a : NEG_SLOPE_C * a;
        w1 = __expf(a);
    }
    float s = w0 + w1;
    for (int j = 64 + l; j < deg; j += 32) {  // cold tail
        int si = ssrc[off0 + j];
        float a = asrc[si] + adi + sae[off0 + j];
        a = (a > 0.f) ? a : NEG_SLOPE_C * a;
        s += __expf(a);
    }
#pragma unroll
    for (int o = 16; o > 0; o >>= 1) s += __shfl_xor(s, o, 32);
    float inv = 1.0f / (s + 1e-16f);

    int c8 = l * 8;
    float acc[8];
#pragma unroll
    for (int q = 0; q < 8; ++q) acc[q] = 0.f;

    auto fetch = [&](int j, int& si, float& wv) {
        if (j < 32) {
            si = __shfl(sidx0, j, 32);
            wv = __shfl(w0, j, 32);
        } else if (j < 64) {
            si = __shfl(sidx1, j - 32, 32);
            wv = __shfl(w1, j - 32, 32);
        } else {
            si = ssrc[off0 + j];
            float a = asrc[si] + adi + sae[off0 + j];
            a = (a > 0.f) ? a : NEG_SLOPE_C * a;
            wv = __expf(a);
        }
    };

    int j = 0;
    for (; j + 3 < deg; j += 4) {
        int i0, i1, i2, i3;
        float u0, u1, u2, u3;
        fetch(j, i0, u0);
        fetch(j + 1, i1, u1);
        fetch(j + 2, i2, u2);
        fetch(j + 3, i3, u3);
        short8 h0 = *(const short8*)&H[(long)i0 * HID_C + c8];
        short8 h1 = *(const short8*)&H[(long)i1 * HID_C + c8];
        short8 h2 = *(const short8*)&H[(long)i2 * HID_C + c8];
        short8 h3 = *(const short8*)&H[(long)i3 * HID_C + c8];
#pragma unroll
        for (int q = 0; q < 8; ++q)
            acc[q] += u0 * b2f((unsigned short)h0[q]) + u1 * b2f((unsigned short)h1[q]) +
                      u2 * b2f((unsigned short)h2[q]) + u3 * b2f((unsigned short)h3[q]);
    }
    for (; j < deg; ++j) {
        int i0;
        float u0;
        fetch(j, i0, u0);
        short8 h0 = *(const short8*)&H[(long)i0 * HID_C + c8];
#pragma unroll
        for (int q = 0; q < 8; ++q) acc[q] += u0 * b2f((unsigned short)h0[q]);
    }

    const f32x4* b4 = (const f32x4*)&bias[c8];
    f32x4 bv0 = b4[0], bv1 = b4[1];
    if (mode == 1) {
        unsigned short* o16 = (unsigned short*)outp;
        short8 r;
#pragma unroll
        for (int q = 0; q < 4; ++q)
            r[q] = (short)f2b(fmaxf(acc[q] * inv + bv0[q], 0.f));
#pragma unroll
        for (int q = 0; q < 4; ++q)
            r[4 + q] = (short)f2b(fmaxf(acc[4 + q] * inv + bv1[q], 0.f));
        *(short8*)&o16[(long)node * HID_C + c8] = r;
    } else {
        float* o32 = (float*)outp;
        f32x4 r0, r1;
#pragma unroll
        for (int q = 0; q < 4; ++q) r0[q] = acc[q] * inv + bv0[q];
#pragma unroll
        for (int q = 0; q < 4; ++q) r1[q] = acc[4 + q] * inv + bv1[q];
        *(f32x4*)&o32[(long)node * HID_C + c8] = r0;
        *(f32x4*)&o32[(long)node * HID_C + c8 + 4] = r1;
    }
}

extern "C" void kernel_launch(void* const* d_in, const int* in_sizes, int n_in,
                              void* d_out, int out_size, void* d_ws, size_t ws_size,
                              hipStream_t stream) {
    const float* x     = (const float*)d_in[0];
    const int*   ei    = (const int*)d_in[1];     // [2, E]: row0=src, row1=dst
    const float* eattr = (const float*)d_in[2];
    const float* W1    = (const float*)d_in[3];
    const float* atts1 = (const float*)d_in[4];
    const float* attd1 = (const float*)d_in[5];
    const float* We1   = (const float*)d_in[6];
    const float* atte1 = (const float*)d_in[7];
    const float* b1    = (const float*)d_in[8];
    const float* W2    = (const float*)d_in[9];
    const float* atts2 = (const float*)d_in[10];
    const float* attd2 = (const float*)d_in[11];
    const float* We2   = (const float*)d_in[12];
    const float* atte2 = (const float*)d_in[13];
    const float* b2    = (const float*)d_in[14];
    float* out = (float*)d_out;

    char* ws = (char*)d_ws;
    size_t off = 0;
    auto alloc = [&](size_t bytes) -> void* {
        void* p = ws + off;
        off = (off + bytes + 255) & ~(size_t)255;
        return p;
    };
    int*   deg  = (int*)alloc((size_t)N_NODES_C * 4);
    int*   offs = (int*)alloc(((size_t)N_NODES_C + 1) * 4);
    int*   cur  = (int*)alloc((size_t)N_NODES_C * 4);
    int*   perm = (int*)alloc((size_t)N_EDGES_C * 4);
    int*   ssrc = (int*)alloc((size_t)N_EDGES_C * 4);
    float* sae1 = (float*)alloc((size_t)N_EDGES_C * 4);
    float* sae2 = (float*)alloc((size_t)N_EDGES_C * 4);
    float* asrc = (float*)alloc((size_t)N_NODES_C * 4);
    float* adst = (float*)alloc((size_t)N_NODES_C * 4);
    float* v    = (float*)alloc(64);
    int*   bsum = (int*)alloc(256 * 4);
    int*   boff = (int*)alloc(257 * 4);
    unsigned short* W1t = (unsigned short*)alloc((size_t)HID_C * IN_DIM_C * 2);
    unsigned short* W2t = (unsigned short*)alloc((size_t)HID_C * HID_C * 2);
    unsigned short* h1  = (unsigned short*)alloc((size_t)N_NODES_C * HID_C * 2);  // also h2
    unsigned short* g1  = (unsigned short*)alloc((size_t)N_NODES_C * HID_C * 2);

    const int* src = ei;
    const int* dst = ei + N_EDGES_C;
    int nb = (N_NODES_C + 255) / 256;  // 196

    hipMemsetAsync(deg, 0, (size_t)N_NODES_C * 4, stream);

    k_prep<<<HID_C * HID_C / 256, 256, 0, stream>>>(W1, W2, W1t, W2t);
    k_v12<<<1, 256, 0, stream>>>(We1, atte1, We2, atte2, v);
    k_hist<<<(N_EDGES_C + 255) / 256, 256, 0, stream>>>(dst, deg);
    k_scan1<<<nb, 256, 0, stream>>>(deg, offs, bsum);
    k_scan2<<<1, 256, 0, stream>>>(bsum, boff, nb);
    k_scan3<<<nb, 256, 0, stream>>>(offs, boff);
    hipMemcpyAsync(cur, offs, (size_t)N_NODES_C * 4, hipMemcpyDeviceToDevice, stream);
    k_perm<<<(N_EDGES_C + 255) / 256, 256, 0, stream>>>(dst, cur, perm);
    k_gather<<<(N_EDGES_C + 255) / 256, 256, 0, stream>>>(perm, src, eattr, v, ssrc, sae1, sae2);

    int gemm_grid = (N_NODES_C + 63) / 64;
    // layer 1
    k_gemm_mfma<IN_DIM_C, true><<<gemm_grid, 256, 0, stream>>>(x, W1t, h1);
    k_dots<<<N_NODES_C / 8, 256, 0, stream>>>(h1, atts1, attd1, asrc, adst);
    k_aggr2<<<N_NODES_C / 8, 256, 0, stream>>>(offs, ssrc, sae1, asrc, adst, h1, b1, g1, 1);
    // layer 2 (h2 aliases h1 buffer)
    k_gemm_mfma<HID_C, false><<<gemm_grid, 256, 0, stream>>>(g1, W2t, h1);
    k_dots<<<N_NODES_C / 8, 256, 0, stream>>>(h1, atts2, attd2, asrc, adst);
    k_aggr2<<<N_NODES_C / 8, 256, 0, stream>>>(offs, ssrc, sae2, asrc, adst, h1, b2, out, 0);
}